// Round 8
// baseline (531.322 us; speedup 1.0000x reference)
//
#include <hip/hip_runtime.h>

typedef short  short8  __attribute__((ext_vector_type(8)));
typedef float  floatx4 __attribute__((ext_vector_type(4)));

#define TT 512
#define DD 32
#define HH 128
#define AA 10
#define LOG2E 1.44269504088896340736f

__device__ __forceinline__ unsigned f2bf(float f) {
    unsigned u = __builtin_bit_cast(unsigned, f);
    return (u + 0x7fffu + ((u >> 16) & 1u)) >> 16;   // RNE f32 -> bf16
}

__device__ __forceinline__ short8 cvt8(floatx4 a, floatx4 b) {
    short8 r;
    r[0] = (short)f2bf(a[0]); r[1] = (short)f2bf(a[1]);
    r[2] = (short)f2bf(a[2]); r[3] = (short)f2bf(a[3]);
    r[4] = (short)f2bf(b[0]); r[5] = (short)f2bf(b[1]);
    r[6] = (short)f2bf(b[2]); r[7] = (short)f2bf(b[3]);
    return r;
}

// activations on pre-scaled gates (scale folded into weights/bias)
__device__ __forceinline__ float sig2(float a) {   // a = -x*log2e
    return __builtin_amdgcn_rcpf(1.0f + __builtin_amdgcn_exp2f(a));
}
__device__ __forceinline__ float tanh2(float a) {  // a = 2x*log2e
    return 1.0f - 2.0f * __builtin_amdgcn_rcpf(1.0f + __builtin_amdgcn_exp2f(a));
}

// lgkm-only step barrier: x prefetch loads float across it
__device__ __forceinline__ void step_barrier() {
    asm volatile("s_waitcnt lgkmcnt(0)" ::: "memory");
    __builtin_amdgcn_s_barrier();
    asm volatile("" ::: "memory");
}

// Prepass: x (f32) -> bf16 in d_ws, same [B][T][D] layout.
__global__ __launch_bounds__(256)
void xcvt(const float* __restrict__ x, unsigned short* __restrict__ xb) {
    const long i = (long)blockIdx.x * 256 + threadIdx.x;
    floatx4 a = *(const floatx4*)(x + 8 * i);
    floatx4 b = *(const floatx4*)(x + 8 * i + 4);
    *(short8*)(xb + 8 * i) = cvt8(a, b);
}

// R=2 batch rows/block, 512 blocks of 256 thr -> 2 INDEPENDENT blocks per CU
// (2 waves/SIMD at independent phases: block A's elementwise tail hides under
// block B's MFMA phase -- no shared barrier, unlike the 8-wave layout).
// Wave w owns all 4 gates for j in [32w,32w+32) = 8 tiles x 5 K = 40 MFMA.
// B cols duplicate b = col&1 (8x); lane's own acc regs already hold its
// (b,j) i/f/g/o quad -> 28 cndmask pack, no LDS round-trip.
// h layout: addr(b,j) = b*256 + ((2j + 64b) & 255): conflict-free writes
// (b=0/b=1 land in disjoint bank halves) and conflict-free reads.
template<int USEWS>
__global__ __launch_bounds__(256, 2)
void lstm_fused(const float* __restrict__ x,    const unsigned short* __restrict__ xbf,
                const float* __restrict__ W_ih, const float* __restrict__ W_hh,
                const float* __restrict__ b_ih, const float* __restrict__ b_hh,
                const float* __restrict__ fc_w, const float* __restrict__ fc_b,
                float* __restrict__ out)
{
    __shared__ unsigned short h_lds[2][2 * HH];    // 1 KiB, dbuf
    __shared__ float hq[2][HH + 4];

    const int tid  = threadIdx.x;
    const int lane = tid & 63;
    const int w    = tid >> 6;      // wave 0..3
    const int l15  = lane & 15;
    const int lgrp = lane >> 4;     // k-group 0..3
    const int bloc = l15 & 1;       // batch row of this lane's B-frag

    const long bglob = (long)blockIdx.x * 2 + bloc;

    // ---- resident A-fragments (bf16, gate-scaled) + bias C-operands ----
    // tile (tg, jb): gate rows ga = 128*tg + 32*w + 16*jb + l15
    short8  afr[4][2][5];
    floatx4 biasv[4][2];
    #pragma unroll
    for (int tg = 0; tg < 4; ++tg) {
        const float sc = (tg == 2) ? (2.0f * LOG2E) : (-LOG2E);
        #pragma unroll
        for (int jb = 0; jb < 2; ++jb) {
            const int ga = 128 * tg + 32 * w + 16 * jb + l15;
            #pragma unroll
            for (int s = 0; s < 4; ++s) {
                const float* p = W_hh + ga * HH + 32 * s + 8 * lgrp;
                afr[tg][jb][s] = cvt8(*(const floatx4*)p * sc, *(const floatx4*)(p + 4) * sc);
            }
            {
                const float* p = W_ih + ga * DD + 8 * lgrp;
                afr[tg][jb][4] = cvt8(*(const floatx4*)p * sc, *(const floatx4*)(p + 4) * sc);
            }
            #pragma unroll
            for (int r = 0; r < 4; ++r) {
                const int gd = 128 * tg + 32 * w + 16 * jb + 4 * lgrp + r;
                biasv[tg][jb][r] = (b_ih[gd] + b_hh[gd]) * sc;
            }
        }
    }

    // zero both h buffers: exactly 256 dwords, 256 threads
    ((unsigned*)h_lds)[tid] = 0u;
    __syncthreads();

    // packed-lane mapping: lane owns (b = l15&1, jp)
    const int jbL = (l15 >> 3) & 1;
    const int rL  = (l15 >> 1) & 3;
    const bool sr0 = (rL & 1) != 0;
    const bool sr1 = (rL & 2) != 0;
    const bool sjb = jbL != 0;
    const int bp  = bloc;
    const int jp  = 32 * w + 16 * jbL + 4 * lgrp + rL;

    // hoisted LDS offsets (rotation swizzle)
    const int rdA0 = bloc * 256 + ((       16 * lgrp + 64 * bloc) & 255);
    const int rdA1 = bloc * 256 + (( 64 +  16 * lgrp + 64 * bloc) & 255);
    const int rdA2 = bloc * 256 + ((128 +  16 * lgrp + 64 * bloc) & 255);
    const int rdA3 = bloc * 256 + ((192 +  16 * lgrp + 64 * bloc) & 255);
    const int rdB0 = rdA0 + 512, rdB1 = rdA1 + 512, rdB2 = rdA2 + 512, rdB3 = rdA3 + 512;
    const int wrA  = bp * 256 + ((2 * jp + 64 * bp) & 255);
    const int wrB  = wrA + 512;

    // x for t=0
    short8  xf;
    floatx4 xa, xb_;
    if constexpr (USEWS) {
        xf = *(const short8*)(xbf + (bglob * TT) * DD + 8 * lgrp);
    } else {
        xa  = *(const floatx4*)(x + (bglob * TT) * DD + 8 * lgrp);
        xb_ = *(const floatx4*)(x + (bglob * TT) * DD + 8 * lgrp + 4);
    }

    float cval = 0.f, hval = 0.f;
    const char* lbase = (const char*)h_lds;

    auto STEP = [&](int r0, int r1, int r2, int r3, int wro, int t) {
        short8 xcur;
        const int tn = (t + 1 < TT) ? (t + 1) : (TT - 1);   // uniform
        if constexpr (USEWS) {
            xcur = xf;
            xf = *(const short8*)(xbf + (bglob * TT + tn) * DD + 8 * lgrp);
        } else {
            xcur = cvt8(xa, xb_);
            const float* xp = x + (bglob * TT + tn) * DD + 8 * lgrp;
            xa  = *(const floatx4*)(xp);
            xb_ = *(const floatx4*)(xp + 4);
        }

        short8 hb0 = *(const short8*)(lbase + r0);
        short8 hb1 = *(const short8*)(lbase + r1);
        short8 hb2 = *(const short8*)(lbase + r2);
        short8 hb3 = *(const short8*)(lbase + r3);

        // 8 independent depth-5 MFMA chains; setprio keeps the matrix pipe
        // fed while the co-resident block is in its VALU phase (T5 -- the
        // role diversity prerequisite is now satisfied across blocks)
        floatx4 acc[4][2];
        __builtin_amdgcn_s_setprio(1);
        #pragma unroll
        for (int tg = 0; tg < 4; ++tg)
            #pragma unroll
            for (int jb = 0; jb < 2; ++jb)
                acc[tg][jb] = __builtin_amdgcn_mfma_f32_16x16x32_bf16(afr[tg][jb][4], xcur, biasv[tg][jb], 0, 0, 0);
        #pragma unroll
        for (int tg = 0; tg < 4; ++tg)
            #pragma unroll
            for (int jb = 0; jb < 2; ++jb)
                acc[tg][jb] = __builtin_amdgcn_mfma_f32_16x16x32_bf16(afr[tg][jb][0], hb0, acc[tg][jb], 0, 0, 0);
        #pragma unroll
        for (int tg = 0; tg < 4; ++tg)
            #pragma unroll
            for (int jb = 0; jb < 2; ++jb)
                acc[tg][jb] = __builtin_amdgcn_mfma_f32_16x16x32_bf16(afr[tg][jb][1], hb1, acc[tg][jb], 0, 0, 0);
        #pragma unroll
        for (int tg = 0; tg < 4; ++tg)
            #pragma unroll
            for (int jb = 0; jb < 2; ++jb)
                acc[tg][jb] = __builtin_amdgcn_mfma_f32_16x16x32_bf16(afr[tg][jb][2], hb2, acc[tg][jb], 0, 0, 0);
        #pragma unroll
        for (int tg = 0; tg < 4; ++tg)
            #pragma unroll
            for (int jb = 0; jb < 2; ++jb)
                acc[tg][jb] = __builtin_amdgcn_mfma_f32_16x16x32_bf16(afr[tg][jb][3], hb3, acc[tg][jb], 0, 0, 0);
        __builtin_amdgcn_s_setprio(0);

        // pack via register select: 7 cndmask per gate (jb: 2, r: 4)
        float g4[4];
        #pragma unroll
        for (int tg = 0; tg < 4; ++tg) {
            const float a01 = sr0 ? acc[tg][0][1] : acc[tg][0][0];
            const float a23 = sr0 ? acc[tg][0][3] : acc[tg][0][2];
            const float va  = sr1 ? a23 : a01;
            const float b01 = sr0 ? acc[tg][1][1] : acc[tg][1][0];
            const float b23 = sr0 ? acc[tg][1][3] : acc[tg][1][2];
            const float vb  = sr1 ? b23 : b01;
            g4[tg] = sjb ? vb : va;
        }

        const float iv = sig2(g4[0]);
        const float fv = sig2(g4[1]);
        const float gv = tanh2(g4[2]);
        const float ov = sig2(g4[3]);
        cval = fv * cval + iv * gv;
        hval = ov * tanh2(cval * (2.0f * LOG2E));

        *(unsigned short*)((char*)h_lds + wro) = (unsigned short)f2bf(hval);
        step_barrier();
    };

    #pragma unroll 1
    for (int t = 0; t < TT; t += 2) {
        STEP(rdA0, rdA1, rdA2, rdA3, wrB, t);       // read buf0, write buf1
        STEP(rdB0, rdB1, rdB2, rdB3, wrA, t + 1);   // read buf1, write buf0
    }

    // ---- epilogue: h_n, c_n, q = h @ fc_w^T + fc_b ----
    {
        const long bg = (long)blockIdx.x * 2 + bp;
        out[10240 + bg * HH + jp]          = hval;   // h_n
        out[10240 + 131072 + bg * HH + jp] = cval;   // c_n
        hq[bp][jp] = hval;
    }
    __syncthreads();
    if (tid < 2 * AA) {
        const int b = tid / AA, a = tid - AA * b;
        float s = fc_b[a];
        const float* fw = fc_w + a * HH;
        const float* hr = &hq[b][0];
        #pragma unroll 8
        for (int j = 0; j < HH; ++j) s = fmaf(hr[j], fw[j], s);
        out[((long)blockIdx.x * 2 + b) * AA + a] = s;
    }
}

extern "C" void kernel_launch(void* const* d_in, const int* in_sizes, int n_in,
                              void* d_out, int out_size, void* d_ws, size_t ws_size,
                              hipStream_t stream) {
    const float* x    = (const float*)d_in[0];
    const float* W_ih = (const float*)d_in[1];
    const float* W_hh = (const float*)d_in[2];
    const float* b_ih = (const float*)d_in[3];
    const float* b_hh = (const float*)d_in[4];
    const float* fc_w = (const float*)d_in[5];
    const float* fc_b = (const float*)d_in[6];
    float* out = (float*)d_out;

    const size_t xelems = (size_t)1024 * TT * DD;       // 16.78M
    if (ws_size >= xelems * sizeof(unsigned short)) {
        unsigned short* xb = (unsigned short*)d_ws;
        xcvt<<<dim3(8192), dim3(256), 0, stream>>>(x, xb);
        lstm_fused<1><<<dim3(512), dim3(256), 0, stream>>>(
            x, xb, W_ih, W_hh, b_ih, b_hh, fc_w, fc_b, out);
    } else {
        lstm_fused<0><<<dim3(512), dim3(256), 0, stream>>>(
            x, nullptr, W_ih, W_hh, b_ih, b_hh, fc_w, fc_b, out);
    }
}

// Round 9
// 300.336 us; speedup vs baseline: 1.7691x; 1.7691x over previous
//
#include <hip/hip_runtime.h>

typedef short  short8  __attribute__((ext_vector_type(8)));
typedef float  floatx4 __attribute__((ext_vector_type(4)));

#define TT 512
#define DD 32
#define HH 128
#define AA 10
#define LOG2E 1.44269504088896340736f

__device__ __forceinline__ unsigned f2bf(float f) {
    unsigned u = __builtin_bit_cast(unsigned, f);
    return (u + 0x7fffu + ((u >> 16) & 1u)) >> 16;   // RNE f32 -> bf16
}

__device__ __forceinline__ short8 cvt8(floatx4 a, floatx4 b) {
    short8 r;
    r[0] = (short)f2bf(a[0]); r[1] = (short)f2bf(a[1]);
    r[2] = (short)f2bf(a[2]); r[3] = (short)f2bf(a[3]);
    r[4] = (short)f2bf(b[0]); r[5] = (short)f2bf(b[1]);
    r[6] = (short)f2bf(b[2]); r[7] = (short)f2bf(b[3]);
    return r;
}

// activations on pre-scaled gates (scale folded into weights/bias)
__device__ __forceinline__ float sig2(float a) {   // a = -x*log2e
    return __builtin_amdgcn_rcpf(1.0f + __builtin_amdgcn_exp2f(a));
}
__device__ __forceinline__ float tanh2(float a) {  // a = 2x*log2e
    return 1.0f - 2.0f * __builtin_amdgcn_rcpf(1.0f + __builtin_amdgcn_exp2f(a));
}

// lgkm-only step barrier: x prefetch loads float across it
__device__ __forceinline__ void step_barrier() {
    asm volatile("s_waitcnt lgkmcnt(0)" ::: "memory");
    __builtin_amdgcn_s_barrier();
    asm volatile("" ::: "memory");
}

// Prepass: x (f32) -> bf16 in d_ws, same [B][T][D] layout.
__global__ __launch_bounds__(256)
void xcvt(const float* __restrict__ x, unsigned short* __restrict__ xb) {
    const long i = (long)blockIdx.x * 256 + threadIdx.x;
    floatx4 a = *(const floatx4*)(x + 8 * i);
    floatx4 b = *(const floatx4*)(x + 8 * i + 4);
    *(short8*)(xb + 8 * i) = cvt8(a, b);
}

// One block = 4 batch rows; 256 blocks = 1 per CU.  (R6 structure.)
// NEW vs R6: waves with (w&1)==1 run at s_setprio(1) for the whole kernel.
// Mechanism: the 2 lockstep waves/SIMD otherwise interleave round-robin on
// the matrix pipe, finish their MFMAs together, and serialize the step into
// [MFMA 643c][VALU 696c].  With static priority, the odd wave drains its 20
// MFMAs first and its 348c elementwise tail overlaps the even wave's
// remaining MFMA issue -> step compresses toward max-pipe (~1000c).
template<int USEWS>
__global__ __launch_bounds__(512, 2)
void lstm_fused(const float* __restrict__ x,    const unsigned short* __restrict__ xbf,
                const float* __restrict__ W_ih, const float* __restrict__ W_hh,
                const float* __restrict__ b_ih, const float* __restrict__ b_hh,
                const float* __restrict__ fc_w, const float* __restrict__ fc_b,
                float* __restrict__ out)
{
    __shared__ unsigned short h_lds[2][4 * HH];    // 2 KiB total, dbuf
    __shared__ float hq[4][HH + 4];

    const int tid  = threadIdx.x;
    const int lane = tid & 63;
    const int w    = tid >> 6;
    const int l15  = lane & 15;
    const int lgrp = lane >> 4;     // k-group 0..3
    const int bloc = l15 & 3;       // batch row of this lane's B-frag

    const long bglob = (long)blockIdx.x * 4 + bloc;

    // ---- resident A-fragments (bf16, gate-scaled) + bias C-operands ----
    short8  afr[4][5];
    floatx4 biasv[4];
    #pragma unroll
    for (int tg = 0; tg < 4; ++tg) {
        const float sc = (tg == 2) ? (2.0f * LOG2E) : (-LOG2E);
        const int m  = w + 8 * tg;
        const int ga = 16 * m + l15;
        #pragma unroll
        for (int s = 0; s < 4; ++s) {
            const float* p = W_hh + ga * HH + 32 * s + 8 * lgrp;
            afr[tg][s] = cvt8(*(const floatx4*)p * sc, *(const floatx4*)(p + 4) * sc);
        }
        {
            const float* p = W_ih + ga * DD + 8 * lgrp;
            afr[tg][4] = cvt8(*(const floatx4*)p * sc, *(const floatx4*)(p + 4) * sc);
        }
        #pragma unroll
        for (int r = 0; r < 4; ++r) {
            const int gd = 16 * m + 4 * lgrp + r;
            biasv[tg][r] = (b_ih[gd] + b_hh[gd]) * sc;
        }
    }

    // zero both h buffers: exactly 512 dwords
    ((unsigned*)h_lds)[tid] = 0u;
    __syncthreads();

    // static asymmetric priority: odd waves lead (wave-uniform branch)
    if (w & 1) __builtin_amdgcn_s_setprio(1);

    // packed-lane mapping: quad element rs = l15>>2
    const int rs  = l15 >> 2;
    const bool sb0 = (rs & 1) != 0;
    const bool sb1 = (rs & 2) != 0;
    const int bp  = bloc;
    const int jp  = 16 * w + 4 * lgrp + rs;

    // hoisted LDS offsets (rotation swizzle), named per buffer
    int rdA0, rdA1, rdA2, rdA3, rdB0, rdB1, rdB2, rdB3;
    {
        const int rb = bloc * 256;
        rdA0 = rb + ((64 * 0 + 16 * lgrp + 32 * bloc) & 255);
        rdA1 = rb + ((64 * 1 + 16 * lgrp + 32 * bloc) & 255);
        rdA2 = rb + ((64 * 2 + 16 * lgrp + 32 * bloc) & 255);
        rdA3 = rb + ((64 * 3 + 16 * lgrp + 32 * bloc) & 255);
        rdB0 = rdA0 + 1024; rdB1 = rdA1 + 1024; rdB2 = rdA2 + 1024; rdB3 = rdA3 + 1024;
    }
    const int wrA = bp * 256 + ((2 * jp + 32 * bp) & 255);          // write into buf0
    const int wrB = wrA + 1024;                                      // write into buf1

    // x for t=0
    short8  xf;
    floatx4 xa, xb_;
    if constexpr (USEWS) {
        xf = *(const short8*)(xbf + (bglob * TT) * DD + 8 * lgrp);
    } else {
        xa  = *(const floatx4*)(x + (bglob * TT) * DD + 8 * lgrp);
        xb_ = *(const floatx4*)(x + (bglob * TT) * DD + 8 * lgrp + 4);
    }

    float cval = 0.f, hval = 0.f;
    const char* lbase = (const char*)h_lds;

    auto STEP = [&](int r0, int r1, int r2, int r3, int wro, int t) {
        short8 xcur;
        const int tn = (t + 1 < TT) ? (t + 1) : (TT - 1);   // uniform (SALU)
        if constexpr (USEWS) {
            xcur = xf;
            xf = *(const short8*)(xbf + (bglob * TT + tn) * DD + 8 * lgrp);
        } else {
            xcur = cvt8(xa, xb_);
            const float* xp = x + (bglob * TT + tn) * DD + 8 * lgrp;
            xa  = *(const floatx4*)(xp);
            xb_ = *(const floatx4*)(xp + 4);
        }

        short8 hb0 = *(const short8*)(lbase + r0);
        short8 hb1 = *(const short8*)(lbase + r1);
        short8 hb2 = *(const short8*)(lbase + r2);
        short8 hb3 = *(const short8*)(lbase + r3);

        // one depth-5 chain per tg, 4 independent chains
        floatx4 acc[4];
        #pragma unroll
        for (int tg = 0; tg < 4; ++tg)
            acc[tg] = __builtin_amdgcn_mfma_f32_16x16x32_bf16(afr[tg][4], xcur, biasv[tg], 0, 0, 0);
        #pragma unroll
        for (int tg = 0; tg < 4; ++tg)
            acc[tg] = __builtin_amdgcn_mfma_f32_16x16x32_bf16(afr[tg][0], hb0, acc[tg], 0, 0, 0);
        #pragma unroll
        for (int tg = 0; tg < 4; ++tg)
            acc[tg] = __builtin_amdgcn_mfma_f32_16x16x32_bf16(afr[tg][1], hb1, acc[tg], 0, 0, 0);
        #pragma unroll
        for (int tg = 0; tg < 4; ++tg)
            acc[tg] = __builtin_amdgcn_mfma_f32_16x16x32_bf16(afr[tg][2], hb2, acc[tg], 0, 0, 0);
        #pragma unroll
        for (int tg = 0; tg < 4; ++tg)
            acc[tg] = __builtin_amdgcn_mfma_f32_16x16x32_bf16(afr[tg][3], hb3, acc[tg], 0, 0, 0);

        // pack via register select (rs = l15>>2)
        float g4[4];
        #pragma unroll
        for (int tg = 0; tg < 4; ++tg) {
            const float v01 = sb0 ? acc[tg][1] : acc[tg][0];
            const float v23 = sb0 ? acc[tg][3] : acc[tg][2];
            g4[tg] = sb1 ? v23 : v01;
        }

        const float iv = sig2(g4[0]);
        const float fv = sig2(g4[1]);
        const float gv = tanh2(g4[2]);
        const float ov = sig2(g4[3]);
        cval = fv * cval + iv * gv;
        hval = ov * tanh2(cval * (2.0f * LOG2E));

        *(unsigned short*)((char*)h_lds + wro) = (unsigned short)f2bf(hval);
        step_barrier();
    };

    #pragma unroll 1
    for (int t = 0; t < TT; t += 2) {
        STEP(rdA0, rdA1, rdA2, rdA3, wrB, t);       // read buf0, write buf1
        STEP(rdB0, rdB1, rdB2, rdB3, wrA, t + 1);   // read buf1, write buf0
    }

    __builtin_amdgcn_s_setprio(0);

    // ---- epilogue: h_n, c_n, q = h @ fc_w^T + fc_b ----
    {
        const long bg = (long)blockIdx.x * 4 + bp;
        out[10240 + bg * HH + jp]          = hval;   // h_n
        out[10240 + 131072 + bg * HH + jp] = cval;   // c_n
        hq[bp][jp] = hval;
    }
    __syncthreads();
    if (tid < 4 * AA) {
        const int b = tid / AA, a = tid - AA * b;
        float s = fc_b[a];
        const float* fw = fc_w + a * HH;
        const float* hr = &hq[b][0];
        #pragma unroll 8
        for (int j = 0; j < HH; ++j) s = fmaf(hr[j], fw[j], s);
        out[((long)blockIdx.x * 4 + b) * AA + a] = s;
    }
}

extern "C" void kernel_launch(void* const* d_in, const int* in_sizes, int n_in,
                              void* d_out, int out_size, void* d_ws, size_t ws_size,
                              hipStream_t stream) {
    const float* x    = (const float*)d_in[0];
    const float* W_ih = (const float*)d_in[1];
    const float* W_hh = (const float*)d_in[2];
    const float* b_ih = (const float*)d_in[3];
    const float* b_hh = (const float*)d_in[4];
    const float* fc_w = (const float*)d_in[5];
    const float* fc_b = (const float*)d_in[6];
    float* out = (float*)d_out;

    const size_t xelems = (size_t)1024 * TT * DD;       // 16.78M
    if (ws_size >= xelems * sizeof(unsigned short)) {
        unsigned short* xb = (unsigned short*)d_ws;
        xcvt<<<dim3(8192), dim3(256), 0, stream>>>(x, xb);
        lstm_fused<1><<<dim3(256), dim3(512), 0, stream>>>(
            x, xb, W_ih, W_hh, b_ih, b_hh, fc_w, fc_b, out);
    } else {
        lstm_fused<0><<<dim3(256), dim3(512), 0, stream>>>(
            x, nullptr, W_ih, W_hh, b_ih, b_hh, fc_w, fc_b, out);
    }
}